// Round 9
// baseline (581.942 us; speedup 1.0000x reference)
//
#include <hip/hip_runtime.h>
#include <hip/hip_bf16.h>
#include <math.h>

// ---------------- types / helpers ----------------
typedef float f32x4 __attribute__((ext_vector_type(4)));
typedef short s16x8 __attribute__((ext_vector_type(8)));
typedef unsigned short us;

__device__ __forceinline__ float bf2f(us u){
  union { unsigned int i; float f; } v; v.i = ((unsigned int)u) << 16; return v.f;
}
__device__ __forceinline__ us f2bf(float f){
  union { float f; unsigned int i; } v; v.f = f;
  unsigned int r = v.i + 0x7FFFu + ((v.i >> 16) & 1u);
  return (us)(r >> 16);
}
__device__ __forceinline__ float dot4(f32x4 a, f32x4 b){
  return a.x*b.x + a.y*b.y + a.z*b.z + a.w*b.w;
}
__device__ __forceinline__ f32x4 mfma16(s16x8 a, s16x8 b, f32x4 c){
  return __builtin_amdgcn_mfma_f32_16x16x32_bf16(a, b, c, 0, 0, 0);
}
// async global->LDS, 16B per lane; dst must be wave-uniform base (HW adds lane*16)
__device__ __forceinline__ void gld16(const us* src, us* dst){
  __builtin_amdgcn_global_load_lds(
      (const __attribute__((address_space(1))) unsigned int*)src,
      (__attribute__((address_space(3))) unsigned int*)dst, 16, 0, 0);
}

#define VM_WAIT0()   asm volatile("s_waitcnt vmcnt(0)" ::: "memory")
#define LGKM_WAIT0() asm volatile("s_waitcnt lgkmcnt(0)" ::: "memory")
#define BAR()        __builtin_amdgcn_s_barrier()
#define SCHED_FENCE() __builtin_amdgcn_sched_barrier(0)

// ---------------- 1) time_feature ----------------
__global__ __launch_bounds__(256) void tf_kernel(
    const float* __restrict__ seq, const float* __restrict__ Wsel,
    const float* __restrict__ bsel, const float* __restrict__ Wtime,
    const float* __restrict__ btime, float* __restrict__ tf)
{
  const int bt = blockIdx.x, tid = threadIdx.x;
  __shared__ float w1[64];
  float s = seq[bt];
  if (tid < 64){ float h = s*Wsel[tid] + bsel[tid]; w1[tid] = 1.0f - tanhf(h*h); }
  __syncthreads();
  const float* wrow = Wtime + (size_t)tid*64;
  float acc = btime[tid];
  #pragma unroll 8
  for (int j = 0; j < 64; ++j) acc += w1[j]*wrow[j];
  tf[(size_t)bt*256 + tid] = acc;
}

// ---------------- 2) embed + gate ----------------
struct GateLds {
  float E[32*260];
  float sc[64];
  float tfs[256];
  float gs[256];
};

template<int L, int N>
__device__ __forceinline__ void gate_body(GateLds& S,
    const int* __restrict__ codes, const float* __restrict__ mask,
    const float* __restrict__ emb, const float* __restrict__ tf,
    const float* __restrict__ Wg, const float* __restrict__ bg,
    us* __restrict__ Xg, us* __restrict__ XgT, float scale, int bt)
{
  const int b = bt/40, t = bt - (bt/40)*40;
  const int tid = threadIdx.x, lane = tid & 63, wid = tid >> 6;

  S.tfs[tid] = tf[(size_t)bt*256 + tid];
  #pragma unroll
  for (int l = 0; l < L; ++l){
    int code = codes[bt*L + l];
    float m = mask[bt*L + l];
    S.E[l*260 + tid] = emb[(size_t)code*256 + tid] * m;
  }
  __syncthreads();

  constexpr int RPW = (L + 3)/4;
  #pragma unroll
  for (int rr = 0; rr < RPW; ++rr){
    int l = wid*RPW + rr;
    if (l < L){
      f32x4 e4 = *(const f32x4*)&S.E[l*260 + lane*4];
      f32x4 t4 = *(const f32x4*)&S.tfs[lane*4];
      float p = dot4(e4, t4);
      #pragma unroll
      for (int m = 1; m < 64; m <<= 1) p += __shfl_xor(p, m, 64);
      if (lane == 0) S.sc[l] = p * scale;
    }
  }
  __syncthreads();
  if (wid == 0){
    float p = (lane < L) ? __expf(S.sc[lane]) : 0.f;
    float ss = p;
    #pragma unroll
    for (int m = 1; m < 64; m <<= 1) ss += __shfl_xor(ss, m, 64);
    if (lane < L) S.sc[lane] = p / ss;
  }
  __syncthreads();

  float g = 0.f;
  #pragma unroll
  for (int l = 0; l < L; ++l) g += S.sc[l]*S.E[l*260 + tid];
  S.gs[tid] = g;
  __syncthreads();

  const float* wrow = Wg + (size_t)tid*256;
  float a2 = bg[tid];
  #pragma unroll
  for (int e = 0; e < 256; e += 4){
    f32x4 w4 = *(const f32x4*)&wrow[e];
    f32x4 g4 = *(const f32x4*)&S.gs[e];
    a2 += dot4(w4, g4);
  }
  float g2 = 1.f/(1.f + __expf(-a2));

  us tbuf[L];
  #pragma unroll
  for (int l = 0; l < L; ++l){
    us h = f2bf(g2 * S.E[l*260 + tid]);
    Xg[((size_t)b*N + t*L + l)*256 + tid] = h;
    tbuf[l] = h;
  }
  size_t tb = ((size_t)b*256 + tid)*N + (size_t)t*L;
  #pragma unroll
  for (int l = 0; l < L; l += 8){
    uint4 v;
    v.x = (unsigned)tbuf[l+0] | ((unsigned)tbuf[l+1] << 16);
    v.y = (unsigned)tbuf[l+2] | ((unsigned)tbuf[l+3] << 16);
    v.z = (unsigned)tbuf[l+4] | ((unsigned)tbuf[l+5] << 16);
    v.w = (unsigned)tbuf[l+6] | ((unsigned)tbuf[l+7] << 16);
    *(uint4*)&XgT[tb + l] = v;
  }
}

template<int L, int N>
__global__ __launch_bounds__(256) void gate_kernel(
    const int* codes, const float* mask, const float* emb, const float* tf,
    const float* Wg, const float* bg, us* Xg, us* XgT, float scale)
{
  __shared__ GateLds S;
  gate_body<L,N>(S, codes, mask, emb, tf, Wg, bg, Xg, XgT, scale, blockIdx.x);
}

__global__ __launch_bounds__(256) void gate_fused(
    const int* mc, const int* dc, const int* pc,
    const float* mm, const float* dm, const float* pm,
    const float* em, const float* ed, const float* ep,
    const float* tf,
    const float* Wgm, const float* bgm, const float* Wgd, const float* bgd,
    const float* Wgp, const float* bgp,
    us* Xm, us* XTm, us* Xd, us* XTd, us* Xp, us* XTp, float scale)
{
  __shared__ GateLds S;
  int bid = blockIdx.x;
  if (bid < 1280)      gate_body<24,960 >(S, mc, mm, em, tf, Wgm, bgm, Xm, XTm, scale, bid);
  else if (bid < 2560) gate_body<32,1280>(S, dc, dm, ed, tf, Wgd, bgd, Xd, XTd, scale, bid-1280);
  else                 gate_body<16,640 >(S, pc, pm, ep, tf, Wgp, bgp, Xp, XTp, scale, bid-2560);
}

// ---------------- 3) visit self-attention (R4 base + V-direct-to-register) ----------------
// K via LDS (single 16KB buffer, gld16, swizzled; overwrite staged under PV,
// full vmcnt(0) drain per tile -> no counted-wait invariants).
// V DIRECT global->register (quarter-A before QK, quarter-B before PV;
// 16KB V tile is L1/L2-resident, 4x reuse per CU) -> PV has zero LDS reads.
// P via R4's per-wave [32][40] bf16 scratch. Row-sums via immediate ONES MFMA.
// LDS padded to 84KB: force 1 block/CU (R5 lesson: >1 block/CU thrashes L2).
struct VisitLds {
  us ks[8192];      // 16 KB: K tile, 32 rows x 512 B, XOR-swizzled
  us ps[4*32*40];   // 10 KB: per-wave P scratch [32][40]
  us pad[29696];    // pad -> 86016 B total: exactly 1 block/CU
};

__device__ __forceinline__ void stage_K(VisitLds& S, const us* __restrict__ Xb,
                                        int k0, int tid)
{
  const int wid = tid >> 6;
  #pragma unroll
  for (int i = 0; i < 4; ++i){
    int c = tid + i*256;
    int row = c >> 5, ch = c & 31;
    gld16(Xb + (size_t)(k0 + row)*256 + (((ch*16) ^ ((row & 7) << 4)) >> 1),
          S.ks + (i*256 + wid*64)*8);
  }
}

template<int N>
__device__ __forceinline__ void visit_body(VisitLds& S,
    const us* __restrict__ Xb, const us* __restrict__ XTb,
    us* __restrict__ Outb, float scale, int q0)
{
  const int tid = threadIdx.x, lane = tid & 63, wid = tid >> 6;
  const int lc = lane & 15, lg = lane >> 4;

  // ---- direct-register Q loads ----
  s16x8 qf[2][8];
  #pragma unroll
  for (int qg = 0; qg < 2; ++qg)
    #pragma unroll
    for (int kk = 0; kk < 8; ++kk){
      int gr = q0 + wid*32 + qg*16 + lc;
      gr = gr < N ? gr : N-1;
      qf[qg][kk] = *(const s16x8*)(Xb + (size_t)gr*256 + kk*32 + lg*8);
    }
  SCHED_FENCE();

  // prologue: stage K(0), full drain (simple and safe)
  stage_K(S, Xb, 0, tid);
  SCHED_FENCE();
  VM_WAIT0();
  BAR();

  // immediate ones fragment for row sums (bf16 1.0 = 0x3F80)
  s16x8 ONES;
  #pragma unroll
  for (int i = 0; i < 8; ++i) ONES[i] = (short)0x3F80;

  f32x4 o[2][16];
  #pragma unroll
  for (int qg = 0; qg < 2; ++qg)
    #pragma unroll
    for (int dcc = 0; dcc < 16; ++dcc) o[qg][dcc] = (f32x4){0.f,0.f,0.f,0.f};
  f32x4 ls[2] = {(f32x4){0.f,0.f,0.f,0.f}, (f32x4){0.f,0.f,0.f,0.f}};

  us* pw = S.ps + wid*32*40;
  const int nt = N/32;

  for (int t = 0; t < nt; ++t){
    const int kb0 = t*32 + lg*8;

    // ---- quarter-A V loads (d 0..127): L1/L2 latency hides under QK ----
    s16x8 va[8];
    #pragma unroll
    for (int dcc = 0; dcc < 8; ++dcc)
      va[dcc] = *(const s16x8*)(XTb + (size_t)(dcc*16 + lc)*N + kb0);

    // ---- S = Q K^T (R4-exact, non-swapped) ----
    f32x4 s[2][2];
    #pragma unroll
    for (int qg = 0; qg < 2; ++qg)
      #pragma unroll
      for (int kc = 0; kc < 2; ++kc) s[qg][kc] = (f32x4){0.f,0.f,0.f,0.f};

    __builtin_amdgcn_s_setprio(1);
    #pragma unroll
    for (int kk = 0; kk < 8; ++kk){
      #pragma unroll
      for (int kc = 0; kc < 2; ++kc){
        int row = kc*16 + lc;
        int off = kk*64 + lg*16;
        s16x8 kb = *(const s16x8*)((const char*)S.ks + row*512 + (off ^ ((row & 7) << 4)));
        s[0][kc] = mfma16(qf[0][kk], kb, s[0][kc]);
        s[1][kc] = mfma16(qf[1][kk], kb, s[1][kc]);
      }
    }
    __builtin_amdgcn_s_setprio(0);

    // ---- softmax numerator -> bf16 P scratch -> A-fragments (R4-exact) ----
    #pragma unroll
    for (int qg = 0; qg < 2; ++qg){
      #pragma unroll
      for (int r = 0; r < 4; ++r){
        float p0 = __expf(s[qg][0][r] * scale);
        float p1 = __expf(s[qg][1][r] * scale);
        int prow = qg*16 + lg*4 + r;
        pw[prow*40 + lc]      = f2bf(p0);
        pw[prow*40 + 16 + lc] = f2bf(p1);
      }
    }
    s16x8 pa[2];
    #pragma unroll
    for (int qg = 0; qg < 2; ++qg)
      pa[qg] = *(const s16x8*)(pw + (qg*16 + lc)*40 + lg*8);

    // ---- quarter-B V loads (d 128..255): latency hides under PV-A ----
    s16x8 vb[8];
    #pragma unroll
    for (int dcc = 0; dcc < 8; ++dcc)
      vb[dcc] = *(const s16x8*)(XTb + (size_t)((dcc + 8)*16 + lc)*N + kb0);

    // all waves done reading ks -> safe to overwrite under PV
    SCHED_FENCE();
    LGKM_WAIT0();
    BAR();
    if (t + 1 < nt) stage_K(S, Xb, (t+1)*32, tid);

    // ---- O += P V ; row-sums via immediate ONES fragment (no LDS reads) ----
    __builtin_amdgcn_s_setprio(1);
    #pragma unroll
    for (int dcc = 0; dcc < 8; ++dcc){
      o[0][dcc] = mfma16(pa[0], va[dcc], o[0][dcc]);
      o[1][dcc] = mfma16(pa[1], va[dcc], o[1][dcc]);
    }
    #pragma unroll
    for (int dcc = 0; dcc < 8; ++dcc){
      o[0][dcc + 8] = mfma16(pa[0], vb[dcc], o[0][dcc + 8]);
      o[1][dcc + 8] = mfma16(pa[1], vb[dcc], o[1][dcc + 8]);
    }
    ls[0] = mfma16(pa[0], ONES, ls[0]);
    ls[1] = mfma16(pa[1], ONES, ls[1]);
    __builtin_amdgcn_s_setprio(0);

    if (t + 1 < nt){
      SCHED_FENCE();
      VM_WAIT0();   // K(t+1) fully landed (issued before PV; mostly hidden)
      BAR();        // visible to all waves
      SCHED_FENCE();
    }
  }

  // epilogue: ONES makes every lane hold its row-sum directly
  #pragma unroll
  for (int qg = 0; qg < 2; ++qg){
    #pragma unroll
    for (int r = 0; r < 4; ++r){
      float inv = 1.f / ls[qg][r];
      int grow = q0 + wid*32 + qg*16 + lg*4 + r;
      if (grow < N){
        #pragma unroll
        for (int dcc = 0; dcc < 16; ++dcc){
          Outb[(size_t)grow*256 + dcc*16 + lc] = f2bf(o[qg][dcc][r] * inv);
        }
      }
    }
  }
}

template<int N>
__global__ __launch_bounds__(256) void visit_kernel(
    const us* Xg, const us* XgT, us* Out, float scale)
{
  __shared__ VisitLds S;
  const int b = blockIdx.y;
  visit_body<N>(S, Xg + (size_t)b*N*256, XgT + (size_t)b*256*N,
                Out + (size_t)b*N*256, scale, blockIdx.x*128);
}

__global__ __launch_bounds__(256) void visit_fused(
    const us* Xm, const us* XTm, us* Am,
    const us* Xd, const us* XTd, us* Ad,
    const us* Xp, const us* XTp, us* Ap, float scale)
{
  __shared__ VisitLds S;
  // XCD-locality remap (736 = 8*92): contiguous logical chunk per XCD.
  // Longest-first: diag (40 tiles), med (30), proc (20).
  int p = blockIdx.x;
  int l = (p & 7)*92 + (p >> 3);
  if (l < 320){
    int b = l/10, q0 = (l - (l/10)*10)*128;
    visit_body<1280>(S, Xd + (size_t)b*1280*256, XTd + (size_t)b*256*1280,
                     Ad + (size_t)b*1280*256, scale, q0);
  } else if (l < 576){
    int r = l - 320, b = r >> 3, q0 = (r & 7)*128;
    visit_body<960>(S, Xm + (size_t)b*960*256, XTm + (size_t)b*256*960,
                    Am + (size_t)b*960*256, scale, q0);
  } else {
    int r = l - 576, b = r/5, q0 = (r - (r/5)*5)*128;
    visit_body<640>(S, Xp + (size_t)b*640*256, XTp + (size_t)b*256*640,
                    Ap + (size_t)b*640*256, scale, q0);
  }
}

// ---------------- 4) merge attention + med_att, fused per (b,t), all-MFMA GEMMs ----------------
__global__ __launch_bounds__(512, 4) void merge_kernel(
    const us* __restrict__ Amed, const us* __restrict__ Adiag,
    const us* __restrict__ Aproc, const float* __restrict__ tf,
    const float* __restrict__ bias, const int* __restrict__ ilen,
    float* __restrict__ out, float scale)
{
  __shared__ alignas(16) us A[80*256];    // 40960 B
  __shared__ alignas(16) us SrB[80*96];   // 15360 B
  us* Mb  = A;                             // phases 1-2 (dead after 2)
  us* Pb  = A;                             // phases 3+ (7680 shorts)
  us* W1B = A + 7680;                      // 3072 shorts
  float* wj  = (float*)(A + 10752);        // 73 floats
  float* uk  = (float*)(A + 10912);        // 73 floats
  float* S2f = (float*)SrB;                // aliases SrB after phase 4

  const int bt = blockIdx.x, b = bt/40, t = bt - (bt/40)*40;
  const int tid = threadIdx.x, lane = tid & 63, wid = tid >> 6;
  const int lc = lane & 15, lg = lane >> 4;

  for (int c = tid; c < 72*32; c += 512){
    int row = c >> 5, ch = c & 31;
    const us* src;
    if (row < 24)      src = Amed  + ((size_t)b*960  + t*24 + row)*256      + ch*8;
    else if (row < 56) src = Adiag + ((size_t)b*1280 + t*32 + (row-24))*256 + ch*8;
    else               src = Aproc + ((size_t)b*640  + t*16 + (row-56))*256 + ch*8;
    uint4 v = *(const uint4*)src;
    *(uint4*)((char*)Mb + row*512 + ((ch*16) ^ ((row & 7) << 4))) = v;
  }
  if (tid < 256) Mb[72*256 + tid] = f2bf(tf[(size_t)bt*256 + tid]);
  for (int c = tid; c < 7*32; c += 512){
    int row = 73 + (c >> 5), ch = c & 31;
    *(uint4*)((char*)Mb + row*512 + ch*16) = (uint4){0,0,0,0};
  }
  __syncthreads();

  for (int tt = wid; tt < 25; tt += 8){
    int ti = tt/5, tj = tt - (tt/5)*5;
    f32x4 s = (f32x4){0.f,0.f,0.f,0.f};
    #pragma unroll
    for (int kk = 0; kk < 8; ++kk){
      int ra = ti*16 + lc, rb = tj*16 + lc;
      int off = kk*64 + lg*16;
      s16x8 a  = *(const s16x8*)((const char*)Mb + ra*512 + (off ^ ((ra & 7) << 4)));
      s16x8 bb = *(const s16x8*)((const char*)Mb + rb*512 + (off ^ ((rb & 7) << 4)));
      s = mfma16(a, bb, s);
    }
    #pragma unroll
    for (int r = 0; r < 4; ++r)
      SrB[(ti*16 + lg*4 + r)*96 + tj*16 + lc] = f2bf(s[r]);
  }
  __syncthreads();   // Mb dead from here; A reused as Pb/W1B/wj/uk

  for (int c = tid; c < 80*16; c += 512){
    int r = c >> 4;
    SrB[r*96 + 80 + (c & 15)] = 0;
  }
  for (int r = wid; r < 73; r += 8){
    float e0 = __expf(scale * bf2f(SrB[r*96 + lane]));
    float e1 = (lane < 9) ? __expf(scale * bf2f(SrB[r*96 + 64 + lane])) : 0.f;
    float ss = e0 + e1;
    #pragma unroll
    for (int m = 1; m < 64; m <<= 1) ss += __shfl_xor(ss, m, 64);
    float inv = 1.f/ss;
    Pb[r*96 + lane] = f2bf(e0 * inv);
    if (lane < 32) Pb[r*96 + 64 + lane] = (lane < 9) ? f2bf(e1*inv) : (us)0;
  }
  for (int c = tid; c < 7*96; c += 512){
    Pb[73*96 + c] = 0;
  }
  __syncthreads();

  for (int tt = wid; tt < 10; tt += 8){
    int ri = tt/5, cj = tt - (tt/5)*5;
    f32x4 s = (f32x4){0.f,0.f,0.f,0.f};
    #pragma unroll
    for (int kk = 0; kk < 3; ++kk){
      s16x8 a  = *(const s16x8*)(Pb  + (ri*16 + lc)*96 + kk*32 + lg*8);
      s16x8 bb = *(const s16x8*)(SrB + (cj*16 + lc)*96 + kk*32 + lg*8);
      s = mfma16(a, bb, s);
    }
    #pragma unroll
    for (int r = 0; r < 4; ++r)
      W1B[(ri*16 + lg*4 + r)*96 + cj*16 + lc] = f2bf(s[r]);
  }
  if (tid < 512){
    W1B[(tid >> 4)*96 + 80 + (tid & 15)] = 0;
  }
  __syncthreads();

  for (int tt = wid; tt < 10; tt += 8){
    int ri = tt/5, cj = tt - (tt/5)*5;
    f32x4 s = (f32x4){0.f,0.f,0.f,0.f};
    #pragma unroll
    for (int kk = 0; kk < 3; ++kk){
      s16x8 a  = *(const s16x8*)(W1B + (ri*16 + lc)*96 + kk*32 + lg*8);
      s16x8 bb = *(const s16x8*)(Pb  + (cj*16 + lc)*96 + kk*32 + lg*8);
      s = mfma16(a, bb, s);
    }
    #pragma unroll
    for (int r = 0; r < 4; ++r)
      S2f[(ri*16 + lg*4 + r)*84 + cj*16 + lc] = s[r];
  }
  __syncthreads();

  for (int r = wid; r < 24; r += 8){
    float e0 = __expf(S2f[r*84 + lane]);
    float e1 = (lane < 9) ? __expf(S2f[r*84 + 64 + lane]) : 0.f;
    float ss = e0 + e1;
    #pragma unroll
    for (int m = 1; m < 64; m <<= 1) ss += __shfl_xor(ss, m, 64);
    float inv = 1.f/ss;
    S2f[r*84 + lane] = e0*inv;
    if (lane < 12) S2f[r*84 + 64 + lane] = (lane < 9) ? e1*inv : 0.f;
  }
  __syncthreads();

  if (tid < 73){
    float a = 0.f;
    #pragma unroll
    for (int i = 0; i < 24; ++i) a += S2f[i*84 + tid];
    wj[tid] = a;
  }
  __syncthreads();
  if (tid < 73){
    float a = 0.f;
    for (int j = 0; j < 73; ++j) a += wj[j] * bf2f(Pb[j*96 + tid]);
    uk[tid] = a;
  }
  __syncthreads();

  if (tid < 256){
    float acc = bias[tid];
    if (t < ilen[b]){
      float ex = (float)(2*(tid>>1)) * (1.0f/256.0f);
      float dv = powf(10000.f, ex);
      float ang = (float)t / dv;
      acc += (tid & 1) ? cosf(ang) : sinf(ang);
    }
    const us* Am_ = Amed  + ((size_t)b*960  + t*24)*256 + tid;
    #pragma unroll 4
    for (int k = 0; k < 24; ++k) acc += uk[k]      * bf2f(Am_[k*256]);
    const us* Ad_ = Adiag + ((size_t)b*1280 + t*32)*256 + tid;
    #pragma unroll 4
    for (int k = 0; k < 32; ++k) acc += uk[24 + k] * bf2f(Ad_[k*256]);
    const us* Ap_ = Aproc + ((size_t)b*640  + t*16)*256 + tid;
    #pragma unroll 4
    for (int k = 0; k < 16; ++k) acc += uk[56 + k] * bf2f(Ap_[k*256]);
    acc += uk[72] * tf[(size_t)bt*256 + tid];
    out[(size_t)bt*256 + tid] = acc;
  }
}

// ---------------- launch ----------------
extern "C" void kernel_launch(void* const* d_in, const int* in_sizes, int n_in,
                              void* d_out, int out_size, void* d_ws, size_t ws_size,
                              hipStream_t stream)
{
  (void)in_sizes; (void)n_in; (void)out_size;

  const int*   med_codes = (const int*)  d_in[0];
  const int*   diag_codes= (const int*)  d_in[1];
  const int*   proc_codes= (const int*)  d_in[2];
  const float* med_mask  = (const float*)d_in[3];
  const float* diag_mask = (const float*)d_in[4];
  const float* proc_mask = (const float*)d_in[5];
  const float* seq_time  = (const float*)d_in[6];
  const int*   input_len = (const int*)  d_in[7];
  const float* emb_med   = (const float*)d_in[8];
  const float* emb_diag  = (const float*)d_in[9];
  const float* emb_proc  = (const float*)d_in[10];
  const float* bias_med  = (const float*)d_in[11];
  const float* W_sel     = (const float*)d_in[12];
  const float* b_sel     = (const float*)d_in[13];
  const float* W_time    = (const float*)d_in[14];
  const float* b_time    = (const float*)d_in[15];
  const float* Wg_med    = (const float*)d_in[16];
  const float* bg_med    = (const float*)d_in[17];
  const float* Wg_diag   = (const float*)d_in[18];
  const float* bg_diag   = (const float*)d_in[19];
  const float* Wg_proc   = (const float*)d_in[20];
  const float* bg_proc   = (const float*)d_in[21];

  const float scale = (float)(1.0 / sqrt(256.0 + 1e-7));

  char* ws = (char*)d_ws;
  const size_t sz_tf = (size_t)1280*256*4;
  const size_t szA_m = (size_t)32*960*256*2;
  const size_t szA_d = (size_t)32*1280*256*2;
  const size_t szA_p = (size_t)32*640*256*2;

  size_t off = 0;
  float* tf   = (float*)(ws + off); off += sz_tf;
  us* Am      = (us*)(ws + off);    off += szA_m;
  us* Ad      = (us*)(ws + off);    off += szA_d;
  us* Ap      = (us*)(ws + off);    off += szA_p;

  const size_t fused_need = off + 2*(szA_m + szA_d + szA_p);
  tf_kernel<<<1280, 256, 0, stream>>>(seq_time, W_sel, b_sel, W_time, b_time, tf);

  if (ws_size >= fused_need){
    us* Xm  = (us*)(ws + off); off += szA_m;
    us* XTm = (us*)(ws + off); off += szA_m;
    us* Xd  = (us*)(ws + off); off += szA_d;
    us* XTd = (us*)(ws + off); off += szA_d;
    us* Xp  = (us*)(ws + off); off += szA_p;
    us* XTp = (us*)(ws + off); off += szA_p;

    gate_fused<<<3840, 256, 0, stream>>>(
        med_codes, diag_codes, proc_codes, med_mask, diag_mask, proc_mask,
        emb_med, emb_diag, emb_proc, tf,
        Wg_med, bg_med, Wg_diag, bg_diag, Wg_proc, bg_proc,
        Xm, XTm, Xd, XTd, Xp, XTp, scale);

    visit_fused<<<736, 256, 0, stream>>>(Xm, XTm, Am, Xd, XTd, Ad, Xp, XTp, Ap, scale);
  } else {
    us* Xg  = (us*)(ws + off);
    us* XgT = (us*)(ws + off + szA_d);

    gate_kernel<24,960><<<1280, 256, 0, stream>>>(med_codes, med_mask, emb_med, tf, Wg_med, bg_med, Xg, XgT, scale);
    visit_kernel<960><<<dim3(8,32), 256, 0, stream>>>(Xg, XgT, Am, scale);

    gate_kernel<32,1280><<<1280, 256, 0, stream>>>(diag_codes, diag_mask, emb_diag, tf, Wg_diag, bg_diag, Xg, XgT, scale);
    visit_kernel<1280><<<dim3(10,32), 256, 0, stream>>>(Xg, XgT, Ad, scale);

    gate_kernel<16,640><<<1280, 256, 0, stream>>>(proc_codes, proc_mask, emb_proc, tf, Wg_proc, bg_proc, Xg, XgT, scale);
    visit_kernel<640><<<dim3(5,32), 256, 0, stream>>>(Xg, XgT, Ap, scale);
  }

  merge_kernel<<<1280, 512, 0, stream>>>(Am, Ad, Ap, tf, bias_med, input_len, (float*)d_out, scale);
}

// Round 10
// 355.640 us; speedup vs baseline: 1.6363x; 1.6363x over previous
//
#include <hip/hip_runtime.h>
#include <hip/hip_bf16.h>
#include <math.h>

// ---------------- types / helpers ----------------
typedef float f32x4 __attribute__((ext_vector_type(4)));
typedef short s16x8 __attribute__((ext_vector_type(8)));
typedef unsigned short us;

__device__ __forceinline__ float bf2f(us u){
  union { unsigned int i; float f; } v; v.i = ((unsigned int)u) << 16; return v.f;
}
__device__ __forceinline__ us f2bf(float f){
  union { float f; unsigned int i; } v; v.f = f;
  unsigned int r = v.i + 0x7FFFu + ((v.i >> 16) & 1u);
  return (us)(r >> 16);
}
__device__ __forceinline__ float dot4(f32x4 a, f32x4 b){
  return a.x*b.x + a.y*b.y + a.z*b.z + a.w*b.w;
}
__device__ __forceinline__ f32x4 mfma16(s16x8 a, s16x8 b, f32x4 c){
  return __builtin_amdgcn_mfma_f32_16x16x32_bf16(a, b, c, 0, 0, 0);
}
// async global->LDS, 16B per lane; dst must be wave-uniform base (HW adds lane*16)
__device__ __forceinline__ void gld16(const us* src, us* dst){
  __builtin_amdgcn_global_load_lds(
      (const __attribute__((address_space(1))) unsigned int*)src,
      (__attribute__((address_space(3))) unsigned int*)dst, 16, 0, 0);
}

#define VM_WAIT8()   asm volatile("s_waitcnt vmcnt(8)" ::: "memory")
#define VM_WAIT0()   asm volatile("s_waitcnt vmcnt(0)" ::: "memory")
#define LGKM_WAIT0() asm volatile("s_waitcnt lgkmcnt(0)" ::: "memory")
#define PRO_WAIT()   asm volatile("s_waitcnt vmcnt(8) lgkmcnt(0)" ::: "memory")
#define BAR()        __builtin_amdgcn_s_barrier()

// ---------------- 1) time_feature ----------------
__global__ __launch_bounds__(256) void tf_kernel(
    const float* __restrict__ seq, const float* __restrict__ Wsel,
    const float* __restrict__ bsel, const float* __restrict__ Wtime,
    const float* __restrict__ btime, float* __restrict__ tf)
{
  const int bt = blockIdx.x, tid = threadIdx.x;
  __shared__ float w1[64];
  float s = seq[bt];
  if (tid < 64){ float h = s*Wsel[tid] + bsel[tid]; w1[tid] = 1.0f - tanhf(h*h); }
  __syncthreads();
  const float* wrow = Wtime + (size_t)tid*64;
  float acc = btime[tid];
  #pragma unroll 8
  for (int j = 0; j < 64; ++j) acc += w1[j]*wrow[j];
  tf[(size_t)bt*256 + tid] = acc;
}

// ---------------- 2) embed + gate ----------------
struct GateLds {
  float E[32*260];
  float sc[64];
  float tfs[256];
  float gs[256];
};

template<int L, int N>
__device__ __forceinline__ void gate_body(GateLds& S,
    const int* __restrict__ codes, const float* __restrict__ mask,
    const float* __restrict__ emb, const float* __restrict__ tf,
    const float* __restrict__ Wg, const float* __restrict__ bg,
    us* __restrict__ Xg, us* __restrict__ XgT, float scale, int bt)
{
  const int b = bt/40, t = bt - (bt/40)*40;
  const int tid = threadIdx.x, lane = tid & 63, wid = tid >> 6;

  S.tfs[tid] = tf[(size_t)bt*256 + tid];
  #pragma unroll
  for (int l = 0; l < L; ++l){
    int code = codes[bt*L + l];
    float m = mask[bt*L + l];
    S.E[l*260 + tid] = emb[(size_t)code*256 + tid] * m;
  }
  __syncthreads();

  constexpr int RPW = (L + 3)/4;
  #pragma unroll
  for (int rr = 0; rr < RPW; ++rr){
    int l = wid*RPW + rr;
    if (l < L){
      f32x4 e4 = *(const f32x4*)&S.E[l*260 + lane*4];
      f32x4 t4 = *(const f32x4*)&S.tfs[lane*4];
      float p = dot4(e4, t4);
      #pragma unroll
      for (int m = 1; m < 64; m <<= 1) p += __shfl_xor(p, m, 64);
      if (lane == 0) S.sc[l] = p * scale;
    }
  }
  __syncthreads();
  if (wid == 0){
    float p = (lane < L) ? __expf(S.sc[lane]) : 0.f;
    float ss = p;
    #pragma unroll
    for (int m = 1; m < 64; m <<= 1) ss += __shfl_xor(ss, m, 64);
    if (lane < L) S.sc[lane] = p / ss;
  }
  __syncthreads();

  float g = 0.f;
  #pragma unroll
  for (int l = 0; l < L; ++l) g += S.sc[l]*S.E[l*260 + tid];
  S.gs[tid] = g;
  __syncthreads();

  const float* wrow = Wg + (size_t)tid*256;
  float a2 = bg[tid];
  #pragma unroll
  for (int e = 0; e < 256; e += 4){
    f32x4 w4 = *(const f32x4*)&wrow[e];
    f32x4 g4 = *(const f32x4*)&S.gs[e];
    a2 += dot4(w4, g4);
  }
  float g2 = 1.f/(1.f + __expf(-a2));

  us tbuf[L];
  #pragma unroll
  for (int l = 0; l < L; ++l){
    us h = f2bf(g2 * S.E[l*260 + tid]);
    Xg[((size_t)b*N + t*L + l)*256 + tid] = h;
    tbuf[l] = h;
  }
  size_t tb = ((size_t)b*256 + tid)*N + (size_t)t*L;
  #pragma unroll
  for (int l = 0; l < L; l += 8){
    uint4 v;
    v.x = (unsigned)tbuf[l+0] | ((unsigned)tbuf[l+1] << 16);
    v.y = (unsigned)tbuf[l+2] | ((unsigned)tbuf[l+3] << 16);
    v.z = (unsigned)tbuf[l+4] | ((unsigned)tbuf[l+5] << 16);
    v.w = (unsigned)tbuf[l+6] | ((unsigned)tbuf[l+7] << 16);
    *(uint4*)&XgT[tb + l] = v;
  }
}

template<int L, int N>
__global__ __launch_bounds__(256) void gate_kernel(
    const int* codes, const float* mask, const float* emb, const float* tf,
    const float* Wg, const float* bg, us* Xg, us* XgT, float scale)
{
  __shared__ GateLds S;
  gate_body<L,N>(S, codes, mask, emb, tf, Wg, bg, Xg, XgT, scale, blockIdx.x);
}

__global__ __launch_bounds__(256) void gate_fused(
    const int* mc, const int* dc, const int* pc,
    const float* mm, const float* dm, const float* pm,
    const float* em, const float* ed, const float* ep,
    const float* tf,
    const float* Wgm, const float* bgm, const float* Wgd, const float* bgd,
    const float* Wgp, const float* bgp,
    us* Xm, us* XTm, us* Xd, us* XTd, us* Xp, us* XTp, float scale)
{
  __shared__ GateLds S;
  int bid = blockIdx.x;
  if (bid < 1280)      gate_body<24,960 >(S, mc, mm, em, tf, Wgm, bgm, Xm, XTm, scale, bid);
  else if (bid < 2560) gate_body<32,1280>(S, dc, dm, ed, tf, Wgd, bgd, Xd, XTd, scale, bid-1280);
  else                 gate_body<16,640 >(S, pc, pm, ep, tf, Wgp, bgp, Xp, XTp, scale, bid-2560);
}

// ---------------- 3) visit self-attention (CHAMPION schedule, R4-bench 188us) ----------------
// Double-buffered 32-key K/V tiles, 2-deep prefetch, counted vmcnt(8),
// 2 barriers/tile, direct-reg Q, setprio around MFMA clusters.
// LDS kept at exactly 77824B (incl. unused tail slots) to reproduce the
// champion's 1-block/CU residency (L2-span protection, round-5 lesson).
// Deltas vs champion (validated in passing R7/R9 runs, register-only):
//   - row-sums via immediate ONES B-fragment (no ones-tail LDS reads)
//   - shfl-free epilogue (every column of ls holds the row-sum)
struct VisitLds {
  us buf[33792];    // KS0[0,8192) KS1[8192,16384) VS0[16384,25088) VS1[25088,33792)
  us ps[4*32*40];   // per-wave P scratch [32][40]
};

__device__ __forceinline__ void stage_tile(VisitLds& S, int cur,
    const us* __restrict__ Xb, const us* __restrict__ XTb, int k0, int N_, int tid)
{
  const int wid = tid >> 6;
  us* KS = S.buf + cur*8192;
  us* VS = S.buf + 16384 + cur*8704;
  #pragma unroll
  for (int i = 0; i < 4; ++i){
    int c = tid + i*256;
    int row = c >> 5, off = (c & 31) * 16;
    gld16(Xb + (size_t)(k0 + row)*256 + ((off ^ ((row & 7) << 4)) >> 1),
          KS + (size_t)(wid*64 + i*256)*8);
    int d = c >> 2, kslot = c & 3;
    gld16(XTb + (size_t)d*N_ + k0 + kslot*8,
          VS + (size_t)(wid*64 + i*256)*8);
  }
}

template<int N>
__device__ __forceinline__ void visit_body(VisitLds& S,
    const us* __restrict__ Xb, const us* __restrict__ XTb,
    us* __restrict__ Outb, float scale, int q0)
{
  const int tid = threadIdx.x, lane = tid & 63, wid = tid >> 6;
  const int lc = lane & 15, lg = lane >> 4;

  // ---- direct-register Q loads (no LDS round-trip) ----
  s16x8 qf[2][8];
  #pragma unroll
  for (int qg = 0; qg < 2; ++qg)
    #pragma unroll
    for (int kk = 0; kk < 8; ++kk){
      int gr = q0 + wid*32 + qg*16 + lc;
      gr = gr < N ? gr : N-1;
      qf[qg][kk] = *(const s16x8*)(Xb + (size_t)gr*256 + kk*32 + lg*8);
    }

  // immediate ones fragment for row sums (bf16 1.0 = 0x3F80)
  s16x8 ONES;
  #pragma unroll
  for (int i = 0; i < 8; ++i) ONES[i] = (short)0x3F80;

  // prologue: prefetch tiles 0 and 1
  stage_tile(S, 0, Xb, XTb, 0, N, tid);
  stage_tile(S, 1, Xb, XTb, 32, N, tid);
  PRO_WAIT();          // tile 0 landed; tile 1's 8 may fly
  BAR();

  f32x4 o[2][16];
  #pragma unroll
  for (int qg = 0; qg < 2; ++qg)
    #pragma unroll
    for (int dcc = 0; dcc < 16; ++dcc) o[qg][dcc] = (f32x4){0.f,0.f,0.f,0.f};
  f32x4 ls[2] = {(f32x4){0.f,0.f,0.f,0.f}, (f32x4){0.f,0.f,0.f,0.f}};

  us* pw = S.ps + wid*32*40;
  const int nt = N/32;

  auto compute_tile = [&](int c){
    const us* KS = S.buf + c*8192;
    const us* VS = S.buf + 16384 + c*8704;

    f32x4 s[2][2];
    #pragma unroll
    for (int qg = 0; qg < 2; ++qg)
      #pragma unroll
      for (int kc = 0; kc < 2; ++kc) s[qg][kc] = (f32x4){0.f,0.f,0.f,0.f};

    __builtin_amdgcn_s_setprio(1);
    #pragma unroll
    for (int kk = 0; kk < 8; ++kk){
      #pragma unroll
      for (int kc = 0; kc < 2; ++kc){
        int row = kc*16 + lc;
        int off = kk*64 + lg*16;
        s16x8 kb = *(const s16x8*)((const char*)KS + row*512 + (off ^ ((row & 7) << 4)));
        s[0][kc] = mfma16(qf[0][kk], kb, s[0][kc]);
        s[1][kc] = mfma16(qf[1][kk], kb, s[1][kc]);
      }
    }
    __builtin_amdgcn_s_setprio(0);

    #pragma unroll
    for (int qg = 0; qg < 2; ++qg){
      #pragma unroll
      for (int r = 0; r < 4; ++r){
        float p0 = __expf(s[qg][0][r] * scale);
        float p1 = __expf(s[qg][1][r] * scale);
        int prow = qg*16 + lg*4 + r;
        pw[prow*40 + lc]      = f2bf(p0);
        pw[prow*40 + 16 + lc] = f2bf(p1);
      }
    }

    s16x8 pa[2];
    #pragma unroll
    for (int qg = 0; qg < 2; ++qg)
      pa[qg] = *(const s16x8*)(pw + (qg*16 + lc)*40 + lg*8);

    __builtin_amdgcn_s_setprio(1);
    #pragma unroll
    for (int dcc = 0; dcc < 16; ++dcc){
      s16x8 vf = *(const s16x8*)(VS + (dcc*16 + lc)*32 + lg*8);
      o[0][dcc] = mfma16(pa[0], vf, o[0][dcc]);
      o[1][dcc] = mfma16(pa[1], vf, o[1][dcc]);
    }
    ls[0] = mfma16(pa[0], ONES, ls[0]);
    ls[1] = mfma16(pa[1], ONES, ls[1]);
    __builtin_amdgcn_s_setprio(0);
  };

  for (int t = 0; t < nt; ++t){
    compute_tile(t & 1);
    if (t == nt-1) break;
    LGKM_WAIT0();                  // all reads of buf[t&1] retired
    BAR();                         // every wave done reading -> safe to overwrite
    if (t + 2 < nt){
      stage_tile(S, t & 1, Xb, XTb, (t+2)*32, N, tid);
      VM_WAIT8();                  // tile t+1 fully landed (only t+2's 8 may fly)
    } else {
      VM_WAIT0();                  // no new issue: drain to guarantee t+1
    }
    BAR();                         // tile t+1 visible to all waves
  }

  // epilogue: ONES B-operand => every lane's ls[qg][r] is its q-row's sum
  #pragma unroll
  for (int qg = 0; qg < 2; ++qg){
    #pragma unroll
    for (int r = 0; r < 4; ++r){
      float inv = 1.f / ls[qg][r];
      int grow = q0 + wid*32 + qg*16 + lg*4 + r;
      if (grow < N){
        #pragma unroll
        for (int dcc = 0; dcc < 16; ++dcc){
          Outb[(size_t)grow*256 + dcc*16 + lc] = f2bf(o[qg][dcc][r] * inv);
        }
      }
    }
  }
}

template<int N>
__global__ __launch_bounds__(256, 2) void visit_kernel(
    const us* Xg, const us* XgT, us* Out, float scale)
{
  __shared__ VisitLds S;
  const int b = blockIdx.y;
  visit_body<N>(S, Xg + (size_t)b*N*256, XgT + (size_t)b*256*N,
                Out + (size_t)b*N*256, scale, blockIdx.x*128);
}

__global__ __launch_bounds__(256, 2) void visit_fused(
    const us* Xm, const us* XTm, us* Am,
    const us* Xd, const us* XTd, us* Ad,
    const us* Xp, const us* XTp, us* Ap, float scale)
{
  __shared__ VisitLds S;
  // XCD-locality remap (736 = 8*92): contiguous logical chunk per XCD.
  // Longest-first: diag (40 tiles), med (30), proc (20).
  int p = blockIdx.x;
  int l = (p & 7)*92 + (p >> 3);
  if (l < 320){
    int b = l/10, q0 = (l - (l/10)*10)*128;
    visit_body<1280>(S, Xd + (size_t)b*1280*256, XTd + (size_t)b*256*1280,
                     Ad + (size_t)b*1280*256, scale, q0);
  } else if (l < 576){
    int r = l - 320, b = r >> 3, q0 = (r & 7)*128;
    visit_body<960>(S, Xm + (size_t)b*960*256, XTm + (size_t)b*256*960,
                    Am + (size_t)b*960*256, scale, q0);
  } else {
    int r = l - 576, b = r/5, q0 = (r - (r/5)*5)*128;
    visit_body<640>(S, Xp + (size_t)b*640*256, XTp + (size_t)b*256*640,
                    Ap + (size_t)b*640*256, scale, q0);
  }
}

// ---------------- 4) merge attention + med_att, fused per (b,t), all-MFMA GEMMs ----------------
__global__ __launch_bounds__(512, 4) void merge_kernel(
    const us* __restrict__ Amed, const us* __restrict__ Adiag,
    const us* __restrict__ Aproc, const float* __restrict__ tf,
    const float* __restrict__ bias, const int* __restrict__ ilen,
    float* __restrict__ out, float scale)
{
  __shared__ alignas(16) us A[80*256];    // 40960 B
  __shared__ alignas(16) us SrB[80*96];   // 15360 B
  us* Mb  = A;                             // phases 1-2 (dead after 2)
  us* Pb  = A;                             // phases 3+ (7680 shorts)
  us* W1B = A + 7680;                      // 3072 shorts
  float* wj  = (float*)(A + 10752);        // 73 floats
  float* uk  = (float*)(A + 10912);        // 73 floats
  float* S2f = (float*)SrB;                // aliases SrB after phase 4

  const int bt = blockIdx.x, b = bt/40, t = bt - (bt/40)*40;
  const int tid = threadIdx.x, lane = tid & 63, wid = tid >> 6;
  const int lc = lane & 15, lg = lane >> 4;

  for (int c = tid; c < 72*32; c += 512){
    int row = c >> 5, ch = c & 31;
    const us* src;
    if (row < 24)      src = Amed  + ((size_t)b*960  + t*24 + row)*256      + ch*8;
    else if (row < 56) src = Adiag + ((size_t)b*1280 + t*32 + (row-24))*256 + ch*8;
    else               src = Aproc + ((size_t)b*640  + t*16 + (row-56))*256 + ch*8;
    uint4 v = *(const uint4*)src;
    *(uint4*)((char*)Mb + row*512 + ((ch*16) ^ ((row & 7) << 4))) = v;
  }
  if (tid < 256) Mb[72*256 + tid] = f2bf(tf[(size_t)bt*256 + tid]);
  for (int c = tid; c < 7*32; c += 512){
    int row = 73 + (c >> 5), ch = c & 31;
    *(uint4*)((char*)Mb + row*512 + ch*16) = (uint4){0,0,0,0};
  }
  __syncthreads();

  for (int tt = wid; tt < 25; tt += 8){
    int ti = tt/5, tj = tt - (tt/5)*5;
    f32x4 s = (f32x4){0.f,0.f,0.f,0.f};
    #pragma unroll
    for (int kk = 0; kk < 8; ++kk){
      int ra = ti*16 + lc, rb = tj*16 + lc;
      int off = kk*64 + lg*16;
      s16x8 a  = *(const s16x8*)((const char*)Mb + ra*512 + (off ^ ((ra & 7) << 4)));
      s16x8 bb = *(const s16x8*)((const char*)Mb + rb*512 + (off ^ ((rb & 7) << 4)));
      s = mfma16(a, bb, s);
    }
    #pragma unroll
    for (int r = 0; r < 4; ++r)
      SrB[(ti*16 + lg*4 + r)*96 + tj*16 + lc] = f2bf(s[r]);
  }
  __syncthreads();   // Mb dead from here; A reused as Pb/W1B/wj/uk

  for (int c = tid; c < 80*16; c += 512){
    int r = c >> 4;
    SrB[r*96 + 80 + (c & 15)] = 0;
  }
  for (int r = wid; r < 73; r += 8){
    float e0 = __expf(scale * bf2f(SrB[r*96 + lane]));
    float e1 = (lane < 9) ? __expf(scale * bf2f(SrB[r*96 + 64 + lane])) : 0.f;
    float ss = e0 + e1;
    #pragma unroll
    for (int m = 1; m < 64; m <<= 1) ss += __shfl_xor(ss, m, 64);
    float inv = 1.f/ss;
    Pb[r*96 + lane] = f2bf(e0 * inv);
    if (lane < 32) Pb[r*96 + 64 + lane] = (lane < 9) ? f2bf(e1*inv) : (us)0;
  }
  for (int c = tid; c < 7*96; c += 512){
    Pb[73*96 + c] = 0;
  }
  __syncthreads();

  for (int tt = wid; tt < 10; tt += 8){
    int ri = tt/5, cj = tt - (tt/5)*5;
    f32x4 s = (f32x4){0.f,0.f,0.f,0.f};
    #pragma unroll
    for (int kk = 0; kk < 3; ++kk){
      s16x8 a  = *(const s16x8*)(Pb  + (ri*16 + lc)*96 + kk*32 + lg*8);
      s16x8 bb = *(const s16x8*)(SrB + (cj*16 + lc)*96 + kk*32 + lg*8);
      s = mfma16(a, bb, s);
    }
    #pragma unroll
    for (int r = 0; r < 4; ++r)
      W1B[(ri*16 + lg*4 + r)*96 + cj*16 + lc] = f2bf(s[r]);
  }
  if (tid < 512){
    W1B[(tid >> 4)*96 + 80 + (tid & 15)] = 0;
  }
  __syncthreads();

  for (int tt = wid; tt < 10; tt += 8){
    int ri = tt/5, cj = tt - (tt/5)*5;
    f32x4 s = (f32x4){0.f,0.f,0.f,0.f};
    #pragma unroll
    for (int kk = 0; kk < 3; ++kk){
      s16x8 a  = *(const s16x8*)(W1B + (ri*16 + lc)*96 + kk*32 + lg*8);
      s16x8 bb = *(const s16x8*)(Pb  + (cj*16 + lc)*96 + kk*32 + lg*8);
      s = mfma16(a, bb, s);
    }
    #pragma unroll
    for (int r = 0; r < 4; ++r)
      S2f[(ri*16 + lg*4 + r)*84 + cj*16 + lc] = s[r];
  }
  __syncthreads();

  for (int r = wid; r < 24; r += 8){
    float e0 = __expf(S2f[r*84 + lane]);
    float e1 = (lane < 9) ? __expf(S2f[r*84 + 64 + lane]) : 0.f;
    float ss = e0 + e1;
    #pragma unroll
    for (int m = 1; m < 64; m <<= 1) ss += __shfl_xor(ss, m, 64);
    float inv = 1.f/ss;
    S2f[r*84 + lane] = e0*inv;
    if (lane < 12) S2f[r*84 + 64 + lane] = (lane < 9) ? e1*inv : 0.f;
  }
  __syncthreads();

  if (tid < 73){
    float a = 0.f;
    #pragma unroll
    for (int i = 0; i < 24; ++i) a += S2f[i*84 + tid];
    wj[tid] = a;
  }
  __syncthreads();
  if (tid < 73){
    float a = 0.f;
    for (int j = 0; j < 73; ++j) a += wj[j] * bf2f(Pb[j*96 + tid]);
    uk[tid] = a;
  }
  __syncthreads();

  if (tid < 256){
    float acc = bias[tid];
    if (t < ilen[b]){
      float ex = (float)(2*(tid>>1)) * (1.0f/256.0f);
      float dv = powf(10000.f, ex);
      float ang = (float)t / dv;
      acc += (tid & 1) ? cosf(ang) : sinf(ang);
    }
    const us* Am_ = Amed  + ((size_t)b*960  + t*24)*256 + tid;
    #pragma unroll 4
    for (int k = 0; k < 24; ++k) acc += uk[k]      * bf2f(Am_[k*256]);
    const us* Ad_ = Adiag + ((size_t)b*1280 + t*32)*256 + tid;
    #pragma unroll 4
    for (int k = 0; k < 32; ++k) acc += uk[24 + k] * bf2f(Ad_[k*256]);
    const us* Ap_ = Aproc + ((size_t)b*640  + t*16)*256 + tid;
    #pragma unroll 4
    for (int k = 0; k < 16; ++k) acc += uk[56 + k] * bf2f(Ap_[k*256]);
    acc += uk[72] * tf[(size_t)bt*256 + tid];
    out[(size_t)bt*256 + tid] = acc;
  }
}

// ---------------- launch ----------------
extern "C" void kernel_launch(void* const* d_in, const int* in_sizes, int n_in,
                              void* d_out, int out_size, void* d_ws, size_t ws_size,
                              hipStream_t stream)
{
  (void)in_sizes; (void)n_in; (void)out_size;

  const int*   med_codes = (const int*)  d_in[0];
  const int*   diag_codes= (const int*)  d_in[1];
  const int*   proc_codes= (const int*)  d_in[2];
  const float* med_mask  = (const float*)d_in[3];
  const float* diag_mask = (const float*)d_in[4];
  const float* proc_mask = (const float*)d_in[5];
  const float* seq_time  = (const float*)d_in[6];
  const int*   input_len = (const int*)  d_in[7];
  const float* emb_med   = (const float*)d_in[8];
  const float* emb_diag  = (const float*)d_in[9];
  const float* emb_proc  = (const float*)d_in[10];
  const float* bias_med  = (const float*)d_in[11];
  const float* W_sel     = (const float*)d_in[12];
  const float* b_sel     = (const float*)d_in[13];
  const float* W_time    = (const float*)d_in[14];
  const float* b_time    = (const float*)d_in[15];
  const float* Wg_med    = (const float*)d_in[16];
  const float* bg_med    = (const float*)d_in[17];
  const float* Wg_diag   = (const float*)d_in[18];
  const float* bg_diag   = (const float*)d_in[19];
  const float* Wg_proc   = (const float*)d_in[20];
  const float* bg_proc   = (const float*)d_in[21];

  const float scale = (float)(1.0 / sqrt(256.0 + 1e-7));

  char* ws = (char*)d_ws;
  const size_t sz_tf = (size_t)1280*256*4;
  const size_t szA_m = (size_t)32*960*256*2;
  const size_t szA_d = (size_t)32*1280*256*2;
  const size_t szA_p = (size_t)32*640*256*2;

  size_t off = 0;
  float* tf   = (float*)(ws + off); off += sz_tf;
  us* Am      = (us*)(ws + off);    off += szA_m;
  us* Ad      = (us*)(ws + off);    off += szA_d;
  us* Ap      = (us*)(ws + off);    off += szA_p;

  const size_t fused_need = off + 2*(szA_m + szA_d + szA_p);
  tf_kernel<<<1280, 256, 0, stream>>>(seq_time, W_sel, b_sel, W_time, b_time, tf);

  if (ws_size >= fused_need){
    us* Xm  = (us*)(ws + off); off += szA_m;
    us* XTm = (us*)(ws + off); off += szA_m;
    us* Xd  = (us*)(ws + off); off += szA_d;
    us* XTd = (us*)(ws + off); off += szA_d;
    us* Xp  = (us*)(ws + off); off += szA_p;
    us* XTp = (us*)(ws + off); off += szA_p;

    gate_fused<<<3840, 256, 0, stream>>>(
        med_codes, diag_codes, proc_codes, med_mask, diag_mask, proc_mask,
        emb_med, emb_diag, emb_proc, tf,
        Wg_med, bg_med, Wg_diag, bg_diag, Wg_proc, bg_proc,
        Xm, XTm, Xd, XTd, Xp, XTp, scale);

    visit_fused<<<736, 256, 0, stream>>>(Xm, XTm, Am, Xd, XTd, Ad, Xp, XTp, Ap, scale);
  } else {
    us* Xg  = (us*)(ws + off);
    us* XgT = (us*)(ws + off + szA_d);

    gate_kernel<24,960><<<1280, 256, 0, stream>>>(med_codes, med_mask, emb_med, tf, Wg_med, bg_med, Xg, XgT, scale);
    visit_kernel<960><<<dim3(8,32), 256, 0, stream>>>(Xg, XgT, Am, scale);

    gate_kernel<32,1280><<<1280, 256, 0, stream>>>(diag_codes, diag_mask, emb_diag, tf, Wg_diag, bg_diag, Xg, XgT, scale);
    visit_kernel<1280><<<dim3(10,32), 256, 0, stream>>>(Xg, XgT, Ad, scale);

    gate_kernel<16,640><<<1280, 256, 0, stream>>>(proc_codes, proc_mask, emb_proc, tf, Wg_proc, bg_proc, Xg, XgT, scale);
    visit_kernel<640><<<dim3(5,32), 256, 0, stream>>>(Xg, XgT, Ap, scale);
  }

  merge_kernel<<<1280, 512, 0, stream>>>(Am, Ad, Ap, tf, bias_med, input_len, (float*)d_out, scale);
}

// Round 11
// 354.840 us; speedup vs baseline: 1.6400x; 1.0023x over previous
//
#include <hip/hip_runtime.h>
#include <hip/hip_bf16.h>
#include <math.h>

// ---------------- types / helpers ----------------
typedef float f32x4 __attribute__((ext_vector_type(4)));
typedef short s16x8 __attribute__((ext_vector_type(8)));
typedef unsigned short us;

__device__ __forceinline__ float bf2f(us u){
  union { unsigned int i; float f; } v; v.i = ((unsigned int)u) << 16; return v.f;
}
__device__ __forceinline__ us f2bf(float f){
  union { float f; unsigned int i; } v; v.f = f;
  unsigned int r = v.i + 0x7FFFu + ((v.i >> 16) & 1u);
  return (us)(r >> 16);
}
__device__ __forceinline__ float dot4(f32x4 a, f32x4 b){
  return a.x*b.x + a.y*b.y + a.z*b.z + a.w*b.w;
}
__device__ __forceinline__ f32x4 mfma16(s16x8 a, s16x8 b, f32x4 c){
  return __builtin_amdgcn_mfma_f32_16x16x32_bf16(a, b, c, 0, 0, 0);
}
// async global->LDS, 16B per lane; dst must be wave-uniform base (HW adds lane*16)
__device__ __forceinline__ void gld16(const us* src, us* dst){
  __builtin_amdgcn_global_load_lds(
      (const __attribute__((address_space(1))) unsigned int*)src,
      (__attribute__((address_space(3))) unsigned int*)dst, 16, 0, 0);
}

#define VM_WAIT8()   asm volatile("s_waitcnt vmcnt(8)" ::: "memory")
#define VM_WAIT0()   asm volatile("s_waitcnt vmcnt(0)" ::: "memory")
#define LGKM_WAIT0() asm volatile("s_waitcnt lgkmcnt(0)" ::: "memory")
#define PRO_WAIT()   asm volatile("s_waitcnt vmcnt(8) lgkmcnt(0)" ::: "memory")
#define BAR()        __builtin_amdgcn_s_barrier()

// ---------------- 1) time_feature ----------------
__global__ __launch_bounds__(256) void tf_kernel(
    const float* __restrict__ seq, const float* __restrict__ Wsel,
    const float* __restrict__ bsel, const float* __restrict__ Wtime,
    const float* __restrict__ btime, float* __restrict__ tf)
{
  const int bt = blockIdx.x, tid = threadIdx.x;
  __shared__ float w1[64];
  float s = seq[bt];
  if (tid < 64){ float h = s*Wsel[tid] + bsel[tid]; w1[tid] = 1.0f - tanhf(h*h); }
  __syncthreads();
  const float* wrow = Wtime + (size_t)tid*64;
  float acc = btime[tid];
  #pragma unroll 8
  for (int j = 0; j < 64; ++j) acc += w1[j]*wrow[j];
  tf[(size_t)bt*256 + tid] = acc;
}

// ---------------- 2) embed + gate ----------------
struct GateLds {
  float E[32*260];
  float sc[64];
  float tfs[256];
  float gs[256];
};

template<int L, int N>
__device__ __forceinline__ void gate_body(GateLds& S,
    const int* __restrict__ codes, const float* __restrict__ mask,
    const float* __restrict__ emb, const float* __restrict__ tf,
    const float* __restrict__ Wg, const float* __restrict__ bg,
    us* __restrict__ Xg, us* __restrict__ XgT, float scale, int bt)
{
  const int b = bt/40, t = bt - (bt/40)*40;
  const int tid = threadIdx.x, lane = tid & 63, wid = tid >> 6;

  S.tfs[tid] = tf[(size_t)bt*256 + tid];
  #pragma unroll
  for (int l = 0; l < L; ++l){
    int code = codes[bt*L + l];
    float m = mask[bt*L + l];
    S.E[l*260 + tid] = emb[(size_t)code*256 + tid] * m;
  }
  __syncthreads();

  constexpr int RPW = (L + 3)/4;
  #pragma unroll
  for (int rr = 0; rr < RPW; ++rr){
    int l = wid*RPW + rr;
    if (l < L){
      f32x4 e4 = *(const f32x4*)&S.E[l*260 + lane*4];
      f32x4 t4 = *(const f32x4*)&S.tfs[lane*4];
      float p = dot4(e4, t4);
      #pragma unroll
      for (int m = 1; m < 64; m <<= 1) p += __shfl_xor(p, m, 64);
      if (lane == 0) S.sc[l] = p * scale;
    }
  }
  __syncthreads();
  if (wid == 0){
    float p = (lane < L) ? __expf(S.sc[lane]) : 0.f;
    float ss = p;
    #pragma unroll
    for (int m = 1; m < 64; m <<= 1) ss += __shfl_xor(ss, m, 64);
    if (lane < L) S.sc[lane] = p / ss;
  }
  __syncthreads();

  float g = 0.f;
  #pragma unroll
  for (int l = 0; l < L; ++l) g += S.sc[l]*S.E[l*260 + tid];
  S.gs[tid] = g;
  __syncthreads();

  const float* wrow = Wg + (size_t)tid*256;
  float a2 = bg[tid];
  #pragma unroll
  for (int e = 0; e < 256; e += 4){
    f32x4 w4 = *(const f32x4*)&wrow[e];
    f32x4 g4 = *(const f32x4*)&S.gs[e];
    a2 += dot4(w4, g4);
  }
  float g2 = 1.f/(1.f + __expf(-a2));

  us tbuf[L];
  #pragma unroll
  for (int l = 0; l < L; ++l){
    us h = f2bf(g2 * S.E[l*260 + tid]);
    Xg[((size_t)b*N + t*L + l)*256 + tid] = h;
    tbuf[l] = h;
  }
  size_t tb = ((size_t)b*256 + tid)*N + (size_t)t*L;
  #pragma unroll
  for (int l = 0; l < L; l += 8){
    uint4 v;
    v.x = (unsigned)tbuf[l+0] | ((unsigned)tbuf[l+1] << 16);
    v.y = (unsigned)tbuf[l+2] | ((unsigned)tbuf[l+3] << 16);
    v.z = (unsigned)tbuf[l+4] | ((unsigned)tbuf[l+5] << 16);
    v.w = (unsigned)tbuf[l+6] | ((unsigned)tbuf[l+7] << 16);
    *(uint4*)&XgT[tb + l] = v;
  }
}

template<int L, int N>
__global__ __launch_bounds__(256) void gate_kernel(
    const int* codes, const float* mask, const float* emb, const float* tf,
    const float* Wg, const float* bg, us* Xg, us* XgT, float scale)
{
  __shared__ GateLds S;
  gate_body<L,N>(S, codes, mask, emb, tf, Wg, bg, Xg, XgT, scale, blockIdx.x);
}

__global__ __launch_bounds__(256) void gate_fused(
    const int* mc, const int* dc, const int* pc,
    const float* mm, const float* dm, const float* pm,
    const float* em, const float* ed, const float* ep,
    const float* tf,
    const float* Wgm, const float* bgm, const float* Wgd, const float* bgd,
    const float* Wgp, const float* bgp,
    us* Xm, us* XTm, us* Xd, us* XTd, us* Xp, us* XTp, float scale)
{
  __shared__ GateLds S;
  int bid = blockIdx.x;
  if (bid < 1280)      gate_body<24,960 >(S, mc, mm, em, tf, Wgm, bgm, Xm, XTm, scale, bid);
  else if (bid < 2560) gate_body<32,1280>(S, dc, dm, ed, tf, Wgd, bgd, Xd, XTd, scale, bid-1280);
  else                 gate_body<16,640 >(S, pc, pm, ep, tf, Wgp, bgp, Xp, XTp, scale, bid-2560);
}

// ---------------- 3) visit self-attention (CHAMPION schedule — FROZEN) ----------------
struct VisitLds {
  us buf[33792];    // KS0[0,8192) KS1[8192,16384) VS0[16384,25088) VS1[25088,33792)
  us ps[4*32*40];   // per-wave P scratch [32][40]
};

__device__ __forceinline__ void stage_tile(VisitLds& S, int cur,
    const us* __restrict__ Xb, const us* __restrict__ XTb, int k0, int N_, int tid)
{
  const int wid = tid >> 6;
  us* KS = S.buf + cur*8192;
  us* VS = S.buf + 16384 + cur*8704;
  #pragma unroll
  for (int i = 0; i < 4; ++i){
    int c = tid + i*256;
    int row = c >> 5, off = (c & 31) * 16;
    gld16(Xb + (size_t)(k0 + row)*256 + ((off ^ ((row & 7) << 4)) >> 1),
          KS + (size_t)(wid*64 + i*256)*8);
    int d = c >> 2, kslot = c & 3;
    gld16(XTb + (size_t)d*N_ + k0 + kslot*8,
          VS + (size_t)(wid*64 + i*256)*8);
  }
}

template<int N>
__device__ __forceinline__ void visit_body(VisitLds& S,
    const us* __restrict__ Xb, const us* __restrict__ XTb,
    us* __restrict__ Outb, float scale, int q0)
{
  const int tid = threadIdx.x, lane = tid & 63, wid = tid >> 6;
  const int lc = lane & 15, lg = lane >> 4;

  s16x8 qf[2][8];
  #pragma unroll
  for (int qg = 0; qg < 2; ++qg)
    #pragma unroll
    for (int kk = 0; kk < 8; ++kk){
      int gr = q0 + wid*32 + qg*16 + lc;
      gr = gr < N ? gr : N-1;
      qf[qg][kk] = *(const s16x8*)(Xb + (size_t)gr*256 + kk*32 + lg*8);
    }

  s16x8 ONES;
  #pragma unroll
  for (int i = 0; i < 8; ++i) ONES[i] = (short)0x3F80;

  stage_tile(S, 0, Xb, XTb, 0, N, tid);
  stage_tile(S, 1, Xb, XTb, 32, N, tid);
  PRO_WAIT();
  BAR();

  f32x4 o[2][16];
  #pragma unroll
  for (int qg = 0; qg < 2; ++qg)
    #pragma unroll
    for (int dcc = 0; dcc < 16; ++dcc) o[qg][dcc] = (f32x4){0.f,0.f,0.f,0.f};
  f32x4 ls[2] = {(f32x4){0.f,0.f,0.f,0.f}, (f32x4){0.f,0.f,0.f,0.f}};

  us* pw = S.ps + wid*32*40;
  const int nt = N/32;

  auto compute_tile = [&](int c){
    const us* KS = S.buf + c*8192;
    const us* VS = S.buf + 16384 + c*8704;

    f32x4 s[2][2];
    #pragma unroll
    for (int qg = 0; qg < 2; ++qg)
      #pragma unroll
      for (int kc = 0; kc < 2; ++kc) s[qg][kc] = (f32x4){0.f,0.f,0.f,0.f};

    __builtin_amdgcn_s_setprio(1);
    #pragma unroll
    for (int kk = 0; kk < 8; ++kk){
      #pragma unroll
      for (int kc = 0; kc < 2; ++kc){
        int row = kc*16 + lc;
        int off = kk*64 + lg*16;
        s16x8 kb = *(const s16x8*)((const char*)KS + row*512 + (off ^ ((row & 7) << 4)));
        s[0][kc] = mfma16(qf[0][kk], kb, s[0][kc]);
        s[1][kc] = mfma16(qf[1][kk], kb, s[1][kc]);
      }
    }
    __builtin_amdgcn_s_setprio(0);

    #pragma unroll
    for (int qg = 0; qg < 2; ++qg){
      #pragma unroll
      for (int r = 0; r < 4; ++r){
        float p0 = __expf(s[qg][0][r] * scale);
        float p1 = __expf(s[qg][1][r] * scale);
        int prow = qg*16 + lg*4 + r;
        pw[prow*40 + lc]      = f2bf(p0);
        pw[prow*40 + 16 + lc] = f2bf(p1);
      }
    }

    s16x8 pa[2];
    #pragma unroll
    for (int qg = 0; qg < 2; ++qg)
      pa[qg] = *(const s16x8*)(pw + (qg*16 + lc)*40 + lg*8);

    __builtin_amdgcn_s_setprio(1);
    #pragma unroll
    for (int dcc = 0; dcc < 16; ++dcc){
      s16x8 vf = *(const s16x8*)(VS + (dcc*16 + lc)*32 + lg*8);
      o[0][dcc] = mfma16(pa[0], vf, o[0][dcc]);
      o[1][dcc] = mfma16(pa[1], vf, o[1][dcc]);
    }
    ls[0] = mfma16(pa[0], ONES, ls[0]);
    ls[1] = mfma16(pa[1], ONES, ls[1]);
    __builtin_amdgcn_s_setprio(0);
  };

  for (int t = 0; t < nt; ++t){
    compute_tile(t & 1);
    if (t == nt-1) break;
    LGKM_WAIT0();
    BAR();
    if (t + 2 < nt){
      stage_tile(S, t & 1, Xb, XTb, (t+2)*32, N, tid);
      VM_WAIT8();
    } else {
      VM_WAIT0();
    }
    BAR();
  }

  #pragma unroll
  for (int qg = 0; qg < 2; ++qg){
    #pragma unroll
    for (int r = 0; r < 4; ++r){
      float inv = 1.f / ls[qg][r];
      int grow = q0 + wid*32 + qg*16 + lg*4 + r;
      if (grow < N){
        #pragma unroll
        for (int dcc = 0; dcc < 16; ++dcc){
          Outb[(size_t)grow*256 + dcc*16 + lc] = f2bf(o[qg][dcc][r] * inv);
        }
      }
    }
  }
}

template<int N>
__global__ __launch_bounds__(256, 2) void visit_kernel(
    const us* Xg, const us* XgT, us* Out, float scale)
{
  __shared__ VisitLds S;
  const int b = blockIdx.y;
  visit_body<N>(S, Xg + (size_t)b*N*256, XgT + (size_t)b*256*N,
                Out + (size_t)b*N*256, scale, blockIdx.x*128);
}

__global__ __launch_bounds__(256, 2) void visit_fused(
    const us* Xm, const us* XTm, us* Am,
    const us* Xd, const us* XTd, us* Ad,
    const us* Xp, const us* XTp, us* Ap, float scale)
{
  __shared__ VisitLds S;
  int p = blockIdx.x;
  int l = (p & 7)*92 + (p >> 3);
  if (l < 320){
    int b = l/10, q0 = (l - (l/10)*10)*128;
    visit_body<1280>(S, Xd + (size_t)b*1280*256, XTd + (size_t)b*256*1280,
                     Ad + (size_t)b*1280*256, scale, q0);
  } else if (l < 576){
    int r = l - 320, b = r >> 3, q0 = (r & 7)*128;
    visit_body<960>(S, Xm + (size_t)b*960*256, XTm + (size_t)b*256*960,
                    Am + (size_t)b*960*256, scale, q0);
  } else {
    int r = l - 576, b = r/5, q0 = (r - (r/5)*5)*128;
    visit_body<640>(S, Xp + (size_t)b*640*256, XTp + (size_t)b*256*640,
                    Ap + (size_t)b*640*256, scale, q0);
  }
}

// ---------------- 4) merge attention + med_att ----------------
// Change vs R10 (single-variable round): Mb stays LIVE for phase 8 (no global
// re-read of A -- that was a cross-XCD L2-miss / HBM-latency chain); Pb/W1B get
// their own buffers. 79.4 KB LDS x 2 blocks/CU = 158.9 <= 160 KB: occupancy
// unchanged (previous 56.3 KB config was also 2 blocks/CU -- LDS-capped).
// Phase 8 additionally k-split across all 512 threads (36/37 + partial buf).
__global__ __launch_bounds__(512, 4) void merge_kernel(
    const us* __restrict__ Amed, const us* __restrict__ Adiag,
    const us* __restrict__ Aproc, const float* __restrict__ tf,
    const float* __restrict__ bias, const int* __restrict__ ilen,
    float* __restrict__ out, float scale)
{
  __shared__ alignas(16) us Mb[80*256];   // 40960 B, LIVE whole kernel
  __shared__ alignas(16) us SrB[80*96];   // 15360 B, bf16 Sr; aliased f32 S2 after phase 4
  __shared__ alignas(16) us Pb[80*96];    // 15360 B, bf16 P
  __shared__ alignas(16) us W1B[32*96];   //  6144 B, bf16 W1
  __shared__ float wj[73];
  __shared__ float uk[73];
  __shared__ float p8[256];               // phase-8 partials (threads 256-511)
  float* S2f = (float*)SrB;

  const int bt = blockIdx.x, b = bt/40, t = bt - (bt/40)*40;
  const int tid = threadIdx.x, lane = tid & 63, wid = tid >> 6;
  const int lc = lane & 15, lg = lane >> 4;

  // ---- phase 1: stage M (rows 0..71 bf16, row 72 = tf, rows 73..79 zero) ----
  for (int c = tid; c < 72*32; c += 512){
    int row = c >> 5, ch = c & 31;
    const us* src;
    if (row < 24)      src = Amed  + ((size_t)b*960  + t*24 + row)*256      + ch*8;
    else if (row < 56) src = Adiag + ((size_t)b*1280 + t*32 + (row-24))*256 + ch*8;
    else               src = Aproc + ((size_t)b*640  + t*16 + (row-56))*256 + ch*8;
    uint4 v = *(const uint4*)src;
    *(uint4*)((char*)Mb + row*512 + ((ch*16) ^ ((row & 7) << 4))) = v;
  }
  if (tid < 256) Mb[72*256 + tid] = f2bf(tf[(size_t)bt*256 + tid]);
  for (int c = tid; c < 7*32; c += 512){
    int row = 73 + (c >> 5), ch = c & 31;
    *(uint4*)((char*)Mb + row*512 + ch*16) = (uint4){0,0,0,0};
  }
  __syncthreads();

  // ---- phase 2: Sr = M M^T via MFMA (5x5 tiles, K=256), write bf16 ----
  for (int tt = wid; tt < 25; tt += 8){
    int ti = tt/5, tj = tt - (tt/5)*5;
    f32x4 s = (f32x4){0.f,0.f,0.f,0.f};
    #pragma unroll
    for (int kk = 0; kk < 8; ++kk){
      int ra = ti*16 + lc, rb = tj*16 + lc;
      int off = kk*64 + lg*16;
      s16x8 a  = *(const s16x8*)((const char*)Mb + ra*512 + (off ^ ((ra & 7) << 4)));
      s16x8 bb = *(const s16x8*)((const char*)Mb + rb*512 + (off ^ ((rb & 7) << 4)));
      s = mfma16(a, bb, s);
    }
    #pragma unroll
    for (int r = 0; r < 4; ++r)
      SrB[(ti*16 + lg*4 + r)*96 + tj*16 + lc] = f2bf(s[r]);
  }
  __syncthreads();

  // ---- phase 3: P = row-softmax(scale*Sr) cols<73 -> bf16 Pb; pads zeroed ----
  for (int c = tid; c < 80*16; c += 512){
    int r = c >> 4;
    SrB[r*96 + 80 + (c & 15)] = 0;
  }
  for (int r = wid; r < 73; r += 8){
    float e0 = __expf(scale * bf2f(SrB[r*96 + lane]));
    float e1 = (lane < 9) ? __expf(scale * bf2f(SrB[r*96 + 64 + lane])) : 0.f;
    float ss = e0 + e1;
    #pragma unroll
    for (int m = 1; m < 64; m <<= 1) ss += __shfl_xor(ss, m, 64);
    float inv = 1.f/ss;
    Pb[r*96 + lane] = f2bf(e0 * inv);
    if (lane < 32) Pb[r*96 + 64 + lane] = (lane < 9) ? f2bf(e1*inv) : (us)0;
  }
  for (int c = tid; c < 7*96; c += 512){
    Pb[73*96 + c] = 0;
  }
  __syncthreads();

  // ---- phase 4: W1 = P(0:32) * Sr via MFMA (Sr symmetric), K=96, bf16 ----
  for (int tt = wid; tt < 10; tt += 8){
    int ri = tt/5, cj = tt - (tt/5)*5;
    f32x4 s = (f32x4){0.f,0.f,0.f,0.f};
    #pragma unroll
    for (int kk = 0; kk < 3; ++kk){
      s16x8 a  = *(const s16x8*)(Pb  + (ri*16 + lc)*96 + kk*32 + lg*8);
      s16x8 bb = *(const s16x8*)(SrB + (cj*16 + lc)*96 + kk*32 + lg*8);
      s = mfma16(a, bb, s);
    }
    #pragma unroll
    for (int r = 0; r < 4; ++r)
      W1B[(ri*16 + lg*4 + r)*96 + cj*16 + lc] = f2bf(s[r]);
  }
  if (tid < 512){
    W1B[(tid >> 4)*96 + 80 + (tid & 15)] = 0;
  }
  __syncthreads();

  // ---- phase 5: S2 = W1 * P^T via MFMA, K=96, f32 into S2f (aliases SrB) ----
  for (int tt = wid; tt < 10; tt += 8){
    int ri = tt/5, cj = tt - (tt/5)*5;
    f32x4 s = (f32x4){0.f,0.f,0.f,0.f};
    #pragma unroll
    for (int kk = 0; kk < 3; ++kk){
      s16x8 a  = *(const s16x8*)(W1B + (ri*16 + lc)*96 + kk*32 + lg*8);
      s16x8 bb = *(const s16x8*)(Pb  + (cj*16 + lc)*96 + kk*32 + lg*8);
      s = mfma16(a, bb, s);
    }
    #pragma unroll
    for (int r = 0; r < 4; ++r)
      S2f[(ri*16 + lg*4 + r)*84 + cj*16 + lc] = s[r];
  }
  __syncthreads();

  // ---- phase 6: P2 = row-softmax(S2) rows<24, in place ----
  for (int r = wid; r < 24; r += 8){
    float e0 = __expf(S2f[r*84 + lane]);
    float e1 = (lane < 9) ? __expf(S2f[r*84 + 64 + lane]) : 0.f;
    float ss = e0 + e1;
    #pragma unroll
    for (int m = 1; m < 64; m <<= 1) ss += __shfl_xor(ss, m, 64);
    float inv = 1.f/ss;
    S2f[r*84 + lane] = e0*inv;
    if (lane < 12) S2f[r*84 + 64 + lane] = (lane < 9) ? e1*inv : 0.f;
  }
  __syncthreads();

  // ---- phase 7: wj, then uk ----
  if (tid < 73){
    float a = 0.f;
    #pragma unroll
    for (int i = 0; i < 24; ++i) a += S2f[i*84 + tid];
    wj[tid] = a;
  }
  __syncthreads();
  if (tid < 73){
    float a = 0.f;
    for (int j = 0; j < 73; ++j) a += wj[j] * bf2f(Pb[j*96 + tid]);
    uk[tid] = a;
  }
  __syncthreads();

  // ---- phase 8: out = bias + pos + sum_k uk[k]*M[k], M from LDS, k-split ----
  {
    int d = tid & 255;
    int k0 = (tid < 256) ? 0 : 36;
    int k1 = (tid < 256) ? 36 : 73;
    float acc = 0.f;
    for (int k = k0; k < k1; ++k){
      us m = *(const us*)((const char*)Mb + k*512 + ((d*2) ^ ((k & 7) << 4)));
      acc += uk[k] * bf2f(m);
    }
    if (tid >= 256) p8[d] = acc;
    __syncthreads();
    if (tid < 256){
      float r = bias[tid] + acc + p8[tid];
      if (t < ilen[b]){
        float ex = (float)(2*(tid>>1)) * (1.0f/256.0f);
        float dv = powf(10000.f, ex);
        float ang = (float)t / dv;
        r += (tid & 1) ? cosf(ang) : sinf(ang);
      }
      out[(size_t)bt*256 + tid] = r;
    }
  }
}

// ---------------- launch ----------------
extern "C" void kernel_launch(void* const* d_in, const int* in_sizes, int n_in,
                              void* d_out, int out_size, void* d_ws, size_t ws_size,
                              hipStream_t stream)
{
  (void)in_sizes; (void)n_in; (void)out_size;

  const int*   med_codes = (const int*)  d_in[0];
  const int*   diag_codes= (const int*)  d_in[1];
  const int*   proc_codes= (const int*)  d_in[2];
  const float* med_mask  = (const float*)d_in[3];
  const float* diag_mask = (const float*)d_in[4];
  const float* proc_mask = (const float*)d_in[5];
  const float* seq_time  = (const float*)d_in[6];
  const int*   input_len = (const int*)  d_in[7];
  const float* emb_med   = (const float*)d_in[8];
  const float* emb_diag  = (const float*)d_in[9];
  const float* emb_proc  = (const float*)d_in[10];
  const float* bias_med  = (const float*)d_in[11];
  const float* W_sel     = (const float*)d_in[12];
  const float* b_sel     = (const float*)d_in[13];
  const float* W_time    = (const float*)d_in[14];
  const float* b_time    = (const float*)d_in[15];
  const float* Wg_med    = (const float*)d_in[16];
  const float* bg_med    = (const float*)d_in[17];
  const float* Wg_diag   = (const float*)d_in[18];
  const float* bg_diag   = (const float*)d_in[19];
  const float* Wg_proc   = (const float*)d_in[20];
  const float* bg_proc   = (const float*)d_in[21];

  const float scale = (float)(1.0 / sqrt(256.0 + 1e-7));

  char* ws = (char*)d_ws;
  const size_t sz_tf = (size_t)1280*256*4;
  const size_t szA_m = (size_t)32*960*256*2;
  const size_t szA_d = (size_t)32*1280*256*2;
  const size_t szA_p = (size_t)32*640*256*2;

  size_t off = 0;
  float* tf   = (float*)(ws + off); off += sz_tf;
  us* Am      = (us*)(ws + off);    off += szA_m;
  us* Ad      = (us*)(ws + off);    off += szA_d;
  us* Ap      = (us*)(ws + off);    off += szA_p;

  const size_t fused_need = off + 2*(szA_m + szA_d + szA_p);
  tf_kernel<<<1280, 256, 0, stream>>>(seq_time, W_sel, b_sel, W_time, b_time, tf);

  if (ws_size >= fused_need){
    us* Xm  = (us*)(ws + off); off += szA_m;
    us* XTm = (us*)(ws + off); off += szA_m;
    us* Xd  = (us*)(ws + off); off += szA_d;
    us* XTd = (us*)(ws + off); off += szA_d;
    us* Xp  = (us*)(ws + off); off += szA_p;
    us* XTp = (us*)(ws + off); off += szA_p;

    gate_fused<<<3840, 256, 0, stream>>>(
        med_codes, diag_codes, proc_codes, med_mask, diag_mask, proc_mask,
        emb_med, emb_diag, emb_proc, tf,
        Wg_med, bg_med, Wg_diag, bg_diag, Wg_proc, bg_proc,
        Xm, XTm, Xd, XTd, Xp, XTp, scale);

    visit_fused<<<736, 256, 0, stream>>>(Xm, XTm, Am, Xd, XTd, Ad, Xp, XTp, Ap, scale);
  } else {
    us* Xg  = (us*)(ws + off);
    us* XgT = (us*)(ws + off + szA_d);

    gate_kernel<24,960><<<1280, 256, 0, stream>>>(med_codes, med_mask, emb_med, tf, Wg_med, bg_med, Xg, XgT, scale);
    visit_kernel<960><<<dim3(8,32), 256, 0, stream>>>(Xg, XgT, Am, scale);

    gate_kernel<32,1280><<<1280, 256, 0, stream>>>(diag_codes, diag_mask, emb_diag, tf, Wg_diag, bg_diag, Xg, XgT, scale);
    visit_kernel<1280><<<dim3(10,32), 256, 0, stream>>>(Xg, XgT, Ad, scale);

    gate_kernel<16,640><<<1280, 256, 0, stream>>>(proc_codes, proc_mask, emb_proc, tf, Wg_proc, bg_proc, Xg, XgT, scale);
    visit_kernel<640><<<dim3(5,32), 256, 0, stream>>>(Xg, XgT, Ap, scale);
  }

  merge_kernel<<<1280, 512, 0, stream>>>(Am, Ad, Ap, tf, bias_med, input_len, (float*)d_out, scale);
}